// Round 1
// baseline (224.374 us; speedup 1.0000x reference)
//
#include <hip/hip_runtime.h>

// Problem: B=16, T=2048, C=200, H=64 single attention head with key/query padding mask.
// q,k,v = x @ W{q,k,v}; S = (q k^T)*H^-0.5 masked; P = softmax(S); out = P v, padded query rows = 0.
// Strategy: bf16 MFMA (16x16x32) for projection + flash attention; fp32 accumulation throughout.

typedef __attribute__((ext_vector_type(8))) __bf16 bf16x8;
typedef __attribute__((ext_vector_type(4))) float f32x4;

#define T_SEQ 2048
#define C_DIM 200
#define H_DIM 64
#define KPAD 224          // C padded to multiple of 32
#define BT_TOT 32768      // B*T
#define QKV_ELEMS 2097152 // BT*H

// ---------------- Kernel 0: repack weights ----------------
// Wt layout: [3][H=64][KPAD=224] bf16, w0=Wq(*0.125), w1=Wk, w2=Wv; zero-padded k>=200.
__global__ void prep_w(const float* __restrict__ Wk, const float* __restrict__ Wq,
                       const float* __restrict__ Wv, __bf16* __restrict__ Wt) {
    int idx = blockIdx.x * blockDim.x + threadIdx.x;
    if (idx >= 3 * H_DIM * KPAD) return;
    int w = idx / (H_DIM * KPAD);
    int r = idx % (H_DIM * KPAD);
    int n = r / KPAD;   // h
    int k = r % KPAD;   // c
    const float* W = (w == 0) ? Wq : (w == 1) ? Wk : Wv;  // [C][H]
    float val = (k < C_DIM) ? W[k * H_DIM + n] : 0.f;
    if (w == 0) val *= 0.125f;  // fold scale=H^-0.5 into q
    Wt[idx] = (__bf16)val;
}

// ---------------- Kernel 1: QKV projection ----------------
// block = 256 threads (4 waves), each wave does 16 rows -> 64 rows/block; grid = 512.
// Outputs: qb,kb row-major [BT][64] bf16; v transposed vT [B][64][2048] bf16.
__global__ __launch_bounds__(256) void qkv_proj(const float* __restrict__ x,
                                                const __bf16* __restrict__ Wt,
                                                __bf16* __restrict__ qb,
                                                __bf16* __restrict__ kb,
                                                __bf16* __restrict__ vT) {
    const int wave = threadIdx.x >> 6;
    const int lane = threadIdx.x & 63;
    const int l15 = lane & 15;
    const int quad = lane >> 4;
    const int m0 = blockIdx.x * 64 + wave * 16;
    const int row = m0 + l15;  // A-operand row (m = lane&15)
    const float* xr = x + (size_t)row * C_DIM;

    f32x4 acc[3][4] = {};  // [weight][ntile]

    #pragma unroll
    for (int ks = 0; ks < 7; ++ks) {
        const int k0 = ks * 32 + quad * 8;
        bf16x8 a;
        if (k0 + 8 <= C_DIM) {
            const float4 f0 = *(const float4*)(xr + k0);
            const float4 f1 = *(const float4*)(xr + k0 + 4);
            a[0]=(__bf16)f0.x; a[1]=(__bf16)f0.y; a[2]=(__bf16)f0.z; a[3]=(__bf16)f0.w;
            a[4]=(__bf16)f1.x; a[5]=(__bf16)f1.y; a[6]=(__bf16)f1.z; a[7]=(__bf16)f1.w;
        } else {
            #pragma unroll
            for (int j = 0; j < 8; ++j) a[j] = (__bf16)0.f;
        }
        #pragma unroll
        for (int w = 0; w < 3; ++w) {
            #pragma unroll
            for (int t = 0; t < 4; ++t) {
                const bf16x8 b = *(const bf16x8*)(Wt + ((w * 64 + t * 16 + l15) * KPAD + k0));
                acc[w][t] = __builtin_amdgcn_mfma_f32_16x16x32_bf16(a, b, acc[w][t], 0, 0, 0);
            }
        }
    }

    // C/D layout: col = lane&15 (h-tile), row = quad*4 + reg (query row)
    #pragma unroll
    for (int t = 0; t < 4; ++t) {
        const int h = t * 16 + l15;
        #pragma unroll
        for (int r = 0; r < 4; ++r) {
            const int m = m0 + quad * 4 + r;
            qb[(size_t)m * H_DIM + h] = (__bf16)acc[0][t][r];
            kb[(size_t)m * H_DIM + h] = (__bf16)acc[1][t][r];
            const int b_ = m >> 11, tt = m & 2047;
            vT[((size_t)b_ * H_DIM + h) * T_SEQ + tt] = (__bf16)acc[2][t][r];
        }
    }
}

// ---------------- Kernel 2: flash attention ----------------
// grid = (T/64, B); block = 256 (4 waves x 16 queries). Key tiles of 64, 32 iterations.
__global__ __launch_bounds__(256) void attn(const __bf16* __restrict__ qb,
                                            const __bf16* __restrict__ kb,
                                            const __bf16* __restrict__ vT,
                                            const int* __restrict__ pm,
                                            float* __restrict__ out) {
    __shared__ __bf16 Pb[4][16 * 72];  // per-wave P buffer, 72-elem rows (bank-conflict pad)

    const int wave = threadIdx.x >> 6;
    const int lane = threadIdx.x & 63;
    const int l15 = lane & 15;
    const int quad = lane >> 4;
    const int b = blockIdx.y;
    const int q0 = blockIdx.x * 64 + wave * 16;
    const size_t bT = (size_t)b * T_SEQ;

    // Q A-fragments: A[m=lane&15][k=quad*8+j], 2 k-steps covering H=64
    bf16x8 qa[2];
    #pragma unroll
    for (int s = 0; s < 2; ++s)
        qa[s] = *(const bf16x8*)(qb + (bT + q0 + l15) * H_DIM + s * 32 + quad * 8);

    f32x4 oacc[4] = {};      // O[row=quad*4+reg][h=l15+16t]
    float mrow[4], lrow[4];  // per-row online softmax state (rows quad*4+reg)
    #pragma unroll
    for (int r = 0; r < 4; ++r) { mrow[r] = -1e30f; lrow[r] = 0.f; }

    __bf16* P = &Pb[wave][0];

    for (int kt = 0; kt < 32; ++kt) {
        const int key0 = kt * 64;

        // S = Q K^T : B-fragment lane holds K[key0+16n+l15][quad*8+j]
        f32x4 sa[4] = {};
        #pragma unroll
        for (int n = 0; n < 4; ++n) {
            #pragma unroll
            for (int s = 0; s < 2; ++s) {
                const bf16x8 kf = *(const bf16x8*)(kb + (bT + key0 + n * 16 + l15) * H_DIM + s * 32 + quad * 8);
                sa[n] = __builtin_amdgcn_mfma_f32_16x16x32_bf16(qa[s], kf, sa[n], 0, 0, 0);
            }
        }

        // key padding mask for my 4 columns
        bool valid[4];
        #pragma unroll
        for (int n = 0; n < 4; ++n) valid[n] = pm[bT + key0 + n * 16 + l15] != 0;

        // online softmax per row (row r shared by the 16 lanes of this quad)
        float pv[4][4];
        #pragma unroll
        for (int r = 0; r < 4; ++r) {
            float mx = -1e30f;
            #pragma unroll
            for (int n = 0; n < 4; ++n)
                mx = fmaxf(mx, valid[n] ? sa[n][r] : -1e30f);
            #pragma unroll
            for (int d = 1; d < 16; d <<= 1) mx = fmaxf(mx, __shfl_xor(mx, d, 64));
            const float mnew = fmaxf(mrow[r], mx);
            const float alpha = __expf(mrow[r] - mnew);
            float sum = 0.f;
            #pragma unroll
            for (int n = 0; n < 4; ++n) {
                const float p = valid[n] ? __expf(sa[n][r] - mnew) : 0.f;
                pv[n][r] = p;
                sum += p;
            }
            #pragma unroll
            for (int d = 1; d < 16; d <<= 1) sum += __shfl_xor(sum, d, 64);
            lrow[r] = lrow[r] * alpha + sum;
            mrow[r] = mnew;
            #pragma unroll
            for (int t = 0; t < 4; ++t) oacc[t][r] *= alpha;
        }

        // P (C/D layout) -> LDS row-major [16][72]
        #pragma unroll
        for (int n = 0; n < 4; ++n)
            #pragma unroll
            for (int r = 0; r < 4; ++r)
                P[(quad * 4 + r) * 72 + n * 16 + l15] = (__bf16)pv[n][r];
        __syncthreads();

        // re-read P as A-operand: A[m=l15][k=quad*8+j]
        bf16x8 pa[2];
        #pragma unroll
        for (int s = 0; s < 2; ++s)
            pa[s] = *(const bf16x8*)(P + l15 * 72 + s * 32 + quad * 8);

        // O += P V : B-fragment lane holds V[key0+s*32+quad*8+j][h=l15+16t] from vT
        #pragma unroll
        for (int t = 0; t < 4; ++t) {
            #pragma unroll
            for (int s = 0; s < 2; ++s) {
                const bf16x8 vf = *(const bf16x8*)(vT + ((size_t)b * H_DIM + t * 16 + l15) * T_SEQ + key0 + s * 32 + quad * 8);
                oacc[t] = __builtin_amdgcn_mfma_f32_16x16x32_bf16(pa[s], vf, oacc[t], 0, 0, 0);
            }
        }
        __syncthreads();
    }

    // epilogue: divide by l, zero padded query rows
    #pragma unroll
    for (int r = 0; r < 4; ++r) {
        const int q = q0 + quad * 4 + r;
        const bool qv = pm[bT + q] != 0;
        const float inv = (qv && lrow[r] > 0.f) ? 1.0f / lrow[r] : 0.f;
        #pragma unroll
        for (int t = 0; t < 4; ++t)
            out[(bT + q) * H_DIM + t * 16 + l15] = oacc[t][r] * inv;
    }
}

extern "C" void kernel_launch(void* const* d_in, const int* in_sizes, int n_in,
                              void* d_out, int out_size, void* d_ws, size_t ws_size,
                              hipStream_t stream) {
    const float* x  = (const float*)d_in[0];
    const int* pm   = (const int*)d_in[1];
    const float* Wk = (const float*)d_in[2];
    const float* Wq = (const float*)d_in[3];
    const float* Wv = (const float*)d_in[4];
    float* out = (float*)d_out;

    // workspace layout (bf16): qb | kb | vT | Wt  = 3*4MB + 84KB
    __bf16* qb = (__bf16*)d_ws;
    __bf16* kb = qb + QKV_ELEMS;
    __bf16* vT = kb + QKV_ELEMS;
    __bf16* Wt = vT + QKV_ELEMS;

    prep_w<<<dim3((3 * H_DIM * KPAD + 255) / 256), dim3(256), 0, stream>>>(Wk, Wq, Wv, Wt);
    qkv_proj<<<dim3(BT_TOT / 64), dim3(256), 0, stream>>>(x, Wt, qb, kb, vT);
    attn<<<dim3(T_SEQ / 64, 16), dim3(256), 0, stream>>>(qb, kb, vT, pm, out);
}